// Round 12
// baseline (183.835 us; speedup 1.0000x reference)
//
#include <hip/hip_runtime.h>
#include <math.h>

static constexpr int kM = 80;
static constexpr int kT = 4000;
static constexpr int kB = 64;
static constexpr int kLow = kM / 3;                 // 26
static constexpr int kHighStart = 2 * kM / 3;       // 53
static constexpr int kHighCount = kM - kHighStart;  // 27
static constexpr int kTrunc = 12;                   // A_ns^12 = 0.95^192 ~ 5e-5
static constexpr int kHalf = kT / 2;                // 2000
static constexpr int kChunksPerHalf = kHalf / 16;   // 125
#define EPSF 1e-6f
#define LOG2E 1.4426950408889634f

typedef float vfloat4 __attribute__((ext_vector_type(4)));
typedef float vfloat2 __attribute__((ext_vector_type(2)));

__device__ __forceinline__ float hw_exp2(float x) { return __builtin_amdgcn_exp2f(x); }
__device__ __forceinline__ float hw_log2(float x) { return __builtin_amdgcn_logf(x); }

__device__ __forceinline__ float fast_sigmoid(float x) {
    return __builtin_amdgcn_rcpf(1.0f + hw_exp2(-x * LOG2E));
}

// ---------------- Kernel A: gate[b,t] — batched-load quarter-split ----------
// (unchanged from R11 — isolate this round's pcen change)
__global__ __launch_bounds__(256, 4) void gate_kernel(
    const float* __restrict__ mel,
    const float* __restrict__ gate_temp,
    float* __restrict__ gate)
{
    const int lane = threadIdx.x & 63;
    const int wid  = threadIdx.x >> 6;
    const int b    = blockIdx.y;
    const int t0   = blockIdx.x * 256 + lane * 4;
    const bool valid = (t0 < kT);

    const float* base = mel + (size_t)b * kM * kT + t0;
    const int m0 = wid * 20;

    vfloat4 slog = {0.f,0.f,0.f,0.f}, ssum = {0.f,0.f,0.f,0.f};
    vfloat4 slow = {0.f,0.f,0.f,0.f}, shigh = {0.f,0.f,0.f,0.f};

    if (valid) {
        vfloat4 v[20];
        #pragma unroll
        for (int j = 0; j < 20; ++j) {
            v[j] = *reinterpret_cast<const vfloat4*>(base + (size_t)(m0 + j) * kT);
        }
        #pragma unroll
        for (int j = 0; j < 20; ++j) {
            const int m = m0 + j;
            vfloat4 lg;
            lg.x = hw_log2(v[j].x + 1e-8f); lg.y = hw_log2(v[j].y + 1e-8f);
            lg.z = hw_log2(v[j].z + 1e-8f); lg.w = hw_log2(v[j].w + 1e-8f);
            slog += lg;
            ssum += v[j];
            if (m < kLow)        slow  += v[j];
            if (m >= kHighStart) shigh += v[j];
        }
    }

    __shared__ vfloat4 sh[4][4][64];   // 16 KB
    sh[wid][0][lane] = slog;
    sh[wid][1][lane] = ssum;
    sh[wid][2][lane] = slow;
    sh[wid][3][lane] = shigh;
    __syncthreads();

    if (wid == 0 && valid) {
        slog  = sh[0][0][lane] + sh[1][0][lane] + sh[2][0][lane] + sh[3][0][lane];
        ssum  = sh[0][1][lane] + sh[1][1][lane] + sh[2][1][lane] + sh[3][1][lane];
        slow  = sh[0][2][lane] + sh[1][2][lane] + sh[2][2][lane] + sh[3][2][lane];
        shigh = sh[0][3][lane] + sh[1][3][lane] + sh[2][3][lane] + sh[3][3][lane];

        const float gt = gate_temp[0];
        vfloat4 o;
        #pragma unroll
        for (int q = 0; q < 4; ++q) {
            const float geo   = hw_exp2(slog[q] * (1.0f / kM));
            const float arith = ssum[q] * (1.0f / kM) + 1e-8f;
            float sf = geo * __builtin_amdgcn_rcpf(arith);
            sf = fminf(fmaxf(sf, 0.0f), 1.0f);
            const float low  = slow[q]  * (1.0f / kLow);
            const float high = shigh[q] * (1.0f / kHighCount);
            float tilt = low * __builtin_amdgcn_rcpf(low + high + 1e-8f);
            tilt = fminf(fmaxf(tilt, 0.0f), 1.0f);
            const float sfa = sf + (1.0f - sf) * fmaxf(tilt - 0.6f, 0.0f);
            o[q] = fast_sigmoid(gt * (sfa - 0.5f));
        }
        *reinterpret_cast<vfloat4*>(gate + (size_t)b * kT + t0) = o;
    }
}

// ---------------- Kernel B: dual PCEN — half-row blocks (phase de-sync) -----
// R2-R11 showed pcen's mem (~22us) and trans (~20us) phases barely overlap:
// 4-wave blocks load/barrier/compute in lockstep and co-resident blocks
// drain together (VALUBusy 41% + HBM 44% ~ mutually exclusive). This round:
// 2-wave blocks on HALF-rows (grid (2,80,64)=10240; 16 blocks/CU co-resident,
// 40 dispatch generations) so block phases stagger at fine grain.
// Carry at the half boundary: wave-0 lanes 0..11 read [1808,2000) (768 B,
// L2-hot), compute 12 warm-up B's, compose with A^k weights — truncation
// A^12 ~ 5e-5, the same magnitude absmax has tolerated since R5.
__global__ __launch_bounds__(128) void pcen_kernel(
    const float* __restrict__ mel,
    const float* __restrict__ ls_ns, const float* __restrict__ la_ns,
    const float* __restrict__ ld_ns, const float* __restrict__ lr_ns,
    const float* __restrict__ ls_st, const float* __restrict__ la_st,
    const float* __restrict__ ld_st, const float* __restrict__ lr_st,
    const float* __restrict__ gate,
    float* __restrict__ out)
{
    const int half = blockIdx.x;        // 0 or 1
    const int m    = blockIdx.y;
    const int b    = blockIdx.z;

    const float s_ns     = fminf(fmaxf(fast_sigmoid(ls_ns[m]), 0.05f), 0.3f);
    const float alpha_ns = fminf(fmaxf(fast_sigmoid(la_ns[m]), 0.9f), 0.999f);
    const float delta_ns = fminf(fmaxf(hw_exp2(ld_ns[m] * LOG2E), 0.5f), 5.0f);
    const float r_ns     = fminf(fmaxf(fast_sigmoid(lr_ns[m]), 0.05f), 0.25f);
    const float s_st     = fminf(fmaxf(fast_sigmoid(ls_st[m]), 0.05f), 0.3f);
    const float alpha_st = fminf(fmaxf(fast_sigmoid(la_st[m]), 0.9f), 0.999f);
    const float delta_st = fminf(fmaxf(hw_exp2(ld_st[m] * LOG2E), 0.001f), 0.1f);
    const float r_st     = fminf(fmaxf(fast_sigmoid(lr_st[m]), 0.05f), 0.25f);
    const float dr_ns = hw_exp2(r_ns * hw_log2(delta_ns));   // delta^r
    const float dr_st = hw_exp2(r_st * hw_log2(delta_st));

    const vfloat2 a2 = {1.0f - s_ns, 1.0f - s_st};
    const vfloat2 s2 = {s_ns, s_st};
    const vfloat2 d2 = {delta_ns, delta_st};
    const float man = -alpha_ns, mas = -alpha_st;

    const size_t rowoff = ((size_t)b * kM + m) * kT;
    const float* row = mel + rowoff;

    const int i      = threadIdx.x;          // chunk index within half
    const int tstart = half * kHalf;
    const int t0     = tstart + i * 16;
    const bool valid = (i < kChunksPerHalf); // 125 of 128; 126/127 idle

    __shared__ float  sv0;
    __shared__ vfloat2 Btab[kChunksPerHalf];
    __shared__ vfloat2 warmB[kTrunc];

    float x[16];
    float gv[16];
    if (valid) {
        const float4* p = reinterpret_cast<const float4*>(row + t0);
        #pragma unroll
        for (int q = 0; q < 4; ++q) {
            const float4 v = p[q];
            x[4*q+0] = v.x; x[4*q+1] = v.y; x[4*q+2] = v.z; x[4*q+3] = v.w;
        }
        const float4* gp = reinterpret_cast<const float4*>(gate + (size_t)b * kT + t0);
        #pragma unroll
        for (int q = 0; q < 4; ++q) {
            const float4 v = gp[q];
            gv[4*q+0] = v.x; gv[4*q+1] = v.y; gv[4*q+2] = v.z; gv[4*q+3] = v.w;
        }
    }

    if (half == 0 && i == 0) sv0 = x[0];

    // warm-up B's for the half boundary (half==1 only): lanes 0..11 read
    // chunks of [tstart-192, tstart) — coalesced 768 B, L2-hot (same row).
    if (half == 1 && i < kTrunc) {
        const float4* wp = reinterpret_cast<const float4*>(row + tstart - kTrunc * 16 + i * 16);
        vfloat2 wB = {0.0f, 0.0f};
        #pragma unroll
        for (int q = 0; q < 4; ++q) {
            const float4 v = wp[q];
            wB = a2 * wB + s2 * v.x;
            wB = a2 * wB + s2 * v.y;
            wB = a2 * wB + s2 * v.z;
            wB = a2 * wB + s2 * v.w;
        }
        warmB[i] = wB;
    }

    // own chunk offset B_i; transform is v -> A*v + B_i with A = a^16 const
    vfloat2 Bv = {0.0f, 0.0f};
    if (valid) {
        #pragma unroll
        for (int k = 0; k < 16; ++k) {
            Bv = a2 * Bv + s2 * x[k];   // v_pk_fma_f32
        }
        Btab[i] = Bv;
    }
    const vfloat2 p2  = a2 * a2;
    const vfloat2 p4  = p2 * p2;
    const vfloat2 p8  = p4 * p4;
    const vfloat2 A2  = p8 * p8;        // a^16 (data-independent)

    __syncthreads();

    if (valid) {
        // carry: sm = sum_{k<min(i,12)} A^k B_{i-1-k}  (+ A^i * C if i<=12)
        vfloat2 sm = {0.0f, 0.0f};
        vfloat2 pw = {1.0f, 1.0f};
        #pragma unroll
        for (int k = 0; k < kTrunc; ++k) {
            if (k < i) {
                sm = pw * Btab[i - 1 - k] + sm;
                pw = pw * A2;
            }
        }
        if (i <= kTrunc) {
            vfloat2 C2;
            if (half == 0) {
                C2.x = sv0; C2.y = sv0;          // exact x[0] init
            } else {
                C2.x = 0.0f; C2.y = 0.0f;        // truncated warm-up compose
                #pragma unroll
                for (int j = 0; j < kTrunc; ++j) {
                    C2 = A2 * C2 + warmB[j];
                }
            }
            sm = pw * C2 + sm;                   // pw = A^i here
        }

        // streaming main pass over the owned 16 elements
        float4* op = reinterpret_cast<float4*>(out + rowoff + t0);
        #pragma unroll
        for (int q = 0; q < 4; ++q) {
            float4 v;
            #pragma unroll
            for (int j = 0; j < 4; ++j) {
                const int k = 4*q + j;
                const float xv = x[k];
                sm = a2 * sm + s2 * xv;            // v_pk_fma_f32
                vfloat2 g2;
                g2.x = hw_exp2(man * hw_log2(sm.x + EPSF));
                g2.y = hw_exp2(mas * hw_log2(sm.y + EPSF));
                const vfloat2 u2 = g2 * xv + d2;   // v_pk_fma_f32
                const float on = hw_exp2(r_ns * hw_log2(u2.x)) - dr_ns;
                const float os = hw_exp2(r_st * hw_log2(u2.y)) - dr_st;
                (&v.x)[j] = fmaf(gv[k], os - on, on);
            }
            op[q] = v;                              // plain cached stores
        }
    }
}

extern "C" void kernel_launch(void* const* d_in, const int* in_sizes, int n_in,
                              void* d_out, int out_size, void* d_ws, size_t ws_size,
                              hipStream_t stream)
{
    const float* mel       = (const float*)d_in[0];
    const float* ls_ns     = (const float*)d_in[1];
    const float* la_ns     = (const float*)d_in[2];
    const float* ld_ns     = (const float*)d_in[3];
    const float* lr_ns     = (const float*)d_in[4];
    const float* ls_st     = (const float*)d_in[5];
    const float* la_st     = (const float*)d_in[6];
    const float* ld_st     = (const float*)d_in[7];
    const float* lr_st     = (const float*)d_in[8];
    const float* gate_temp = (const float*)d_in[9];
    float* out  = (float*)d_out;
    float* gate = (float*)d_ws;   // kB*kT floats = 1.02 MB scratch

    dim3 gA(16, kB);                     // 1024 blocks, 16 waves/CU
    gate_kernel<<<gA, 256, 0, stream>>>(mel, gate_temp, gate);

    dim3 gB(2, kM, kB);                  // 10240 half-row blocks, 2 waves each
    pcen_kernel<<<gB, 128, 0, stream>>>(mel, ls_ns, la_ns, ld_ns, lr_ns,
                                        ls_st, la_st, ld_st, lr_st, gate, out);
}